// Round 8
// baseline (166.394 us; speedup 1.0000x reference)
//
#include <hip/hip_runtime.h>

typedef _Float16 half_t;
typedef _Float16 v8h __attribute__((ext_vector_type(8)));
typedef _Float16 h2  __attribute__((ext_vector_type(2)));
typedef float f32x16 __attribute__((ext_vector_type(16)));

#define XTP 40   // xt LDS row pitch (halves): 32 data + 8 pad (row = 80B, 16B-aligned)
#define HP  72   // h  LDS row pitch (halves): 64 data + 8 pad (row = 144B, 16B-aligned)

// ===== merged W prep: W (128,K) f32 -> f16 per-32o-stripe streams =====
// chunk(s, t, kk) [512 halves]: lane l holds row o = s*32 + (l&31),
// k = t*32 + kk*16 + (l>>5)*8 + e  (32x32x16 A-frag: row=lane&31, k=(lane>>5)*8+e).
// dst halves = (s*STEPS + t)*1024 + kk*512 + l*8 -> per-wave stream fully contiguous.
__global__ __launch_bounds__(256) void prep_w_all(const float* __restrict__ W0,
                                                  const float* __restrict__ W1,
                                                  const float* __restrict__ W2,
                                                  half_t* __restrict__ w0h,
                                                  half_t* __restrict__ w1h,
                                                  half_t* __restrict__ w2h) {
  int i = blockIdx.x * 256 + threadIdx.x;         // 0..81919 (wave-uniform segments)
  const float* src; half_t* dst; int ktot; int ksh; int j;
  if (i < 16384)      { src = W0; dst = w0h; ktot = 1024; ksh = 7; j = i; }
  else if (i < 49152) { src = W1; dst = w1h; ktot = 2048; ksh = 8; j = i - 16384; }
  else                { src = W2; dst = w2h; ktot = 2048; ksh = 8; j = i - 49152; }
  int o = j >> ksh, k8 = j & ((1 << ksh) - 1);    // lane-consecutive k8: coalesced reads
  const float* s = src + (size_t)o * ktot + k8 * 8;
  float4 f0 = *(const float4*)s;
  float4 f1 = *(const float4*)(s + 4);
  union { half_t h[8]; uint4 u; } pk;
  pk.h[0] = (half_t)f0.x; pk.h[1] = (half_t)f0.y; pk.h[2] = (half_t)f0.z; pk.h[3] = (half_t)f0.w;
  pk.h[4] = (half_t)f1.x; pk.h[5] = (half_t)f1.y; pk.h[6] = (half_t)f1.z; pk.h[7] = (half_t)f1.w;
  int st = o >> 5, r = o & 31;                    // stripe, row-in-stripe
  int t = k8 >> 2, w = k8 & 3;                    // k-step, chunk-within-step
  int kk = w >> 1, hi = w & 1;
  size_t di = ((size_t)(st * (ktot >> 5) + t) * 1024) + kk * 512 + (hi * 32 + r) * 8;
  *(uint4*)(dst + di) = pk.u;
}

// half-broadcast helpers: duplicate one 16-bit half across a 32-bit word
__device__ __forceinline__ unsigned dup_lo(unsigned w) { return (w << 16) | (w & 0xffffu); }
__device__ __forceinline__ unsigned dup_hi(unsigned w) { return (w >> 16) | (w & 0xffff0000u); }

// v8h * broadcast-half via packed f16 muls
__device__ __forceinline__ v8h mul_bcast(v8h h, unsigned xx) {
  union U { v8h v; h2 p[4]; unsigned u[4]; } a, r, x;
  a.v = h; x.u[0] = xx;
#pragma unroll
  for (int i = 0; i < 4; ++i) r.p[i] = a.p[i] * x.p[0];
  return r.v;
}

// ============ one CIN layer: Y = relu(W @ Z + b), Z built on the fly ============
// 4-way M x 2-way N, 32x32x16 MFMA, W streamed global->VGPR, ZERO K-loop barriers.
// Depth-4 register pipeline -- 4 buffer pairs, 8 loads in flight, load-to-use
// distance = 4 wave-steps. All buffer indices compile-time via fully-unrolled
// 4-step groups (no ring math, no copies).
// Fragment maps (harness-verified): A row=lane&31, k=(lane>>5)*8+e; B col=lane&31,
// same k; C/D col=lane&31, row=(reg&3)+8*(reg>>2)+4*(lane>>5).
template <int G, int KTOT, int KEEP, int OUT_BASE, bool H_OUT, bool H_IS_X>
__device__ __forceinline__ void layer(const half_t* __restrict__ wgt,
                                      const float* __restrict__ bias,
                                      const half_t* __restrict__ xt_lds,
                                      half_t* __restrict__ h_lds,
                                      float* __restrict__ out,
                                      size_t b0, int tid) {
  constexpr int STEPS = KTOT / 32;          // K-steps (32 or 64)
  constexpr int SPO   = (G == 64) ? 16 : 8; // steps per f-octet (4 octets); SPO%4==0
  constexpr int NGRP  = SPO / 4;            // 4-step groups per octet
  constexpr int NCH   = (G == 64) ? 4 : 2;  // hreg chunks per n-tile
  const int lane = tid & 63;
  const int wv  = tid >> 6;
  const int ms  = wv & 3;                   // M stripe: o in [ms*32, ms*32+32)
  const int ng  = wv >> 2;                  // N group: batches ng*4 .. ng*4+3
  const int e16 = lane & 15;                // e
  const int bl  = (lane >> 4) & 1;          // batch-sub within 32-col n-tile
  const int khi = lane >> 5;                // k-half selector (8-half granule)

  __syncthreads();   // entry: xt staging / previous layer's h_lds writes visible

  int lrow[2];
#pragma unroll
  for (int nt = 0; nt < 2; ++nt) lrow[nt] = (ng * 4 + nt * 2 + bl) * 16 + e16;

  // ---- h fragments: register-resident for the whole K-loop ----
  const half_t* hb = H_IS_X ? xt_lds : h_lds;
  const int hpitch = H_IS_X ? XTP : HP;
  v8h hreg[2][NCH];
#pragma unroll
  for (int nt = 0; nt < 2; ++nt)
#pragma unroll
    for (int c = 0; c < NCH; ++c) {
      const int off = (G == 64) ? ((c >> 1) * 32 + (c & 1) * 16 + khi * 8)
                                : (c * 16 + khi * 8);
      hreg[nt][c] = *(const v8h*)(hb + lrow[nt] * hpitch + off);
    }

  __syncthreads();   // all waves snapshotted h before anyone's epilogue overwrites it

  // ---- W stream: contiguous per wave; prologue loads steps 0..3 (8 in flight) ----
  const half_t* wl = wgt + (size_t)ms * (STEPS * 1024) + lane * 8;
  v8h pa0 = *(const v8h*)(wl);
  v8h pb0 = *(const v8h*)(wl + 512);
  v8h pa1 = *(const v8h*)(wl + 1024);
  v8h pb1 = *(const v8h*)(wl + 1536);
  v8h pa2 = *(const v8h*)(wl + 2048);
  v8h pb2 = *(const v8h*)(wl + 2560);
  v8h pa3 = *(const v8h*)(wl + 3072);
  v8h pb3 = *(const v8h*)(wl + 3584);
  wl += 4096;                               // -> step 4

  f32x16 acc[2] = {};
  unsigned xwu[2][4];                       // current f-octet of x, u32 view

  auto dostep = [&](v8h a0, v8h a1, int tloc) {
    const int j = (G == 64) ? (tloc >> 1) : tloc;   // f within octet (compile-time)
    unsigned xx[2];
#pragma unroll
    for (int nt = 0; nt < 2; ++nt) {
      const unsigned w = xwu[nt][j >> 1];
      xx[nt] = (j & 1) ? dup_hi(w) : dup_lo(w);     // CSE'd across same-j steps
    }
#pragma unroll
    for (int kk = 0; kk < 2; ++kk) {
      const v8h a = kk ? a1 : a0;
      const int c = (G == 64) ? ((tloc & 1) * 2 + kk) : kk;
#pragma unroll
      for (int nt = 0; nt < 2; ++nt) {
        v8h bfr = mul_bcast(hreg[nt][c], xx[nt]);
        acc[nt] = __builtin_amdgcn_mfma_f32_32x32x16_f16(a, bfr, acc[nt], 0, 0, 0);
      }
    }
  };

  // ---- octets 0..2: every group consumes 4 steps and refills 4 (load for t+4) ----
#pragma unroll 1
  for (int oct = 0; oct < 3; ++oct) {
#pragma unroll
    for (int nt = 0; nt < 2; ++nt) {
      uint4 q = *(const uint4*)(xt_lds + lrow[nt] * XTP + oct * 8);
      xwu[nt][0] = q.x; xwu[nt][1] = q.y; xwu[nt][2] = q.z; xwu[nt][3] = q.w;
    }
#pragma unroll
    for (int gg = 0; gg < NGRP; ++gg) {
      dostep(pa0, pb0, gg * 4 + 0); pa0 = *(const v8h*)(wl);        pb0 = *(const v8h*)(wl + 512);
      dostep(pa1, pb1, gg * 4 + 1); pa1 = *(const v8h*)(wl + 1024); pb1 = *(const v8h*)(wl + 1536);
      dostep(pa2, pb2, gg * 4 + 2); pa2 = *(const v8h*)(wl + 2048); pb2 = *(const v8h*)(wl + 2560);
      dostep(pa3, pb3, gg * 4 + 3); pa3 = *(const v8h*)(wl + 3072); pb3 = *(const v8h*)(wl + 3584);
      wl += 4096;
    }
  }

  // ---- final octet: last group consumes without refilling ----
  {
#pragma unroll
    for (int nt = 0; nt < 2; ++nt) {
      uint4 q = *(const uint4*)(xt_lds + lrow[nt] * XTP + 3 * 8);
      xwu[nt][0] = q.x; xwu[nt][1] = q.y; xwu[nt][2] = q.z; xwu[nt][3] = q.w;
    }
#pragma unroll
    for (int gg = 0; gg < NGRP; ++gg) {
      if (gg < NGRP - 1) {                  // compile-time under full unroll
        dostep(pa0, pb0, gg * 4 + 0); pa0 = *(const v8h*)(wl);        pb0 = *(const v8h*)(wl + 512);
        dostep(pa1, pb1, gg * 4 + 1); pa1 = *(const v8h*)(wl + 1024); pb1 = *(const v8h*)(wl + 1536);
        dostep(pa2, pb2, gg * 4 + 2); pa2 = *(const v8h*)(wl + 2048); pb2 = *(const v8h*)(wl + 2560);
        dostep(pa3, pb3, gg * 4 + 3); pa3 = *(const v8h*)(wl + 3072); pb3 = *(const v8h*)(wl + 3584);
        wl += 4096;
      } else {
        dostep(pa0, pb0, gg * 4 + 0);
        dostep(pa1, pb1, gg * 4 + 1);
        dostep(pa2, pb2, gg * 4 + 2);
        dostep(pa3, pb3, gg * 4 + 3);
      }
    }
  }

  // ---- epilogue: bias + relu; stripes 2,3 -> h_lds (B-layout); o<KEEP -> sum_e -> out ----
  // acc reg = q*4 + r  ->  C row = r + 8*q + 4*khi;  o = ms*32 + row.
  const int obase0 = ms * 32;
#pragma unroll
  for (int nt = 0; nt < 2; ++nt) {
    const int bb = ng * 4 + nt * 2 + bl;
#pragma unroll
    for (int q = 0; q < 4; ++q) {
      const int ob = obase0 + q * 8 + khi * 4;   // rows ob..ob+3
      float4 b4 = *(const float4*)(bias + ob);
      float v[4];
#pragma unroll
      for (int r = 0; r < 4; ++r)
        v[r] = fmaxf(acc[nt][q * 4 + r] + (&b4.x)[r], 0.0f);
      if (H_OUT && obase0 >= 64) {               // wave-uniform
        union { half_t h[4]; uint2 u; } pk;
#pragma unroll
        for (int r = 0; r < 4; ++r) pk.h[r] = (half_t)v[r];
        *(uint2*)(h_lds + (bb * 16 + e16) * HP + (ob - 64)) = pk.u;
      }
      if (obase0 < KEEP) {                       // wave-uniform
#pragma unroll
        for (int r = 0; r < 4; ++r) {
          float sv = v[r];
          sv += __shfl_xor(sv, 1);
          sv += __shfl_xor(sv, 2);
          sv += __shfl_xor(sv, 4);
          sv += __shfl_xor(sv, 8);               // sum over e (16-lane group)
          if (e16 == 0) out[(b0 + bb) * 256 + OUT_BASE + ob + r] = sv;
        }
      }
    }
  }
}

// ============ fused CIN: all 3 layers, one block = 8 batch elements ============
// 512 thr (8 waves), grid 512 -> 2 blocks/CU (16 waves, 4/SIMD -- the reg-tier cap).
// LDS 28KB (xt 10 + h 18). launch_bounds(512,4): 128-VGPR cap; est arch ~100 +
// 32 AGPR acc -> fits the 4-wave tier, no spill (FETCH_SIZE is the tripwire).
__global__ __launch_bounds__(512, 4) void cin_fused(const float* __restrict__ x,
                                                    const half_t* __restrict__ w0h,
                                                    const half_t* __restrict__ w1h,
                                                    const half_t* __restrict__ w2h,
                                                    const float* __restrict__ b0p,
                                                    const float* __restrict__ b1p,
                                                    const float* __restrict__ b2p,
                                                    float* __restrict__ out) {
  __shared__ __align__(16) half_t xt_lds[128 * XTP];
  __shared__ __align__(16) half_t h_lds[128 * HP];

  const int tid = threadIdx.x;
  const size_t b0 = (size_t)blockIdx.x * 8;

  // ---- stage xt from x f32 (b,f,e) -> LDS (b,e) rows x 32 f, f16 ----
#pragma unroll
  for (int i = 0; i < 2; ++i) {
    int idx = (i * 512 + tid) * 4;             // 0..4095 by 4 (e%4==0 within one f,b)
    float4 v = *(const float4*)(x + b0 * 512 + idx);
    int e = idx & 15, f = (idx >> 4) & 31, b = idx >> 9;
    half_t* d = xt_lds + (b * 16 + e) * XTP + f;
    d[0 * XTP] = (half_t)v.x;
    d[1 * XTP] = (half_t)v.y;
    d[2 * XTP] = (half_t)v.z;
    d[3 * XTP] = (half_t)v.w;
  }

  // layer 0: G=32 (h = x0), keep o<64 -> out ch [0,64), o>=64 -> h_lds
  layer<32, 1024, 64, 0, true, true>(w0h, b0p, xt_lds, h_lds, out, b0, tid);
  // layer 1: G=64, keep o<64 -> out ch [64,128), o>=64 -> h_lds (overwrite)
  layer<64, 2048, 64, 64, true, false>(w1h, b1p, xt_lds, h_lds, out, b0, tid);
  // layer 2: G=64, keep all 128 -> out ch [128,256)
  layer<64, 2048, 128, 128, false, false>(w2h, b2p, xt_lds, h_lds, out, b0, tid);
}

extern "C" void kernel_launch(void* const* d_in, const int* in_sizes, int n_in,
                              void* d_out, int out_size, void* d_ws, size_t ws_size,
                              hipStream_t stream) {
  const float* x  = (const float*)d_in[0];
  const float* W0 = (const float*)d_in[1];
  const float* b0 = (const float*)d_in[2];
  const float* W1 = (const float*)d_in[3];
  const float* b1 = (const float*)d_in[4];
  const float* W2 = (const float*)d_in[5];
  const float* b2 = (const float*)d_in[6];
  float* out = (float*)d_out;
  char* ws = (char*)d_ws;

  half_t* w0h = (half_t*)(ws);                       // 256 KB
  half_t* w1h = (half_t*)(ws + (256u << 10));        // 512 KB
  half_t* w2h = (half_t*)(ws + (768u << 10));        // 512 KB

  prep_w_all<<<320, 256, 0, stream>>>(W0, W1, W2, w0h, w1h, w2h);
  cin_fused<<<512, 512, 0, stream>>>(x, w0h, w1h, w2h, b0, b1, b2, out);
}

// Round 9
// 152.277 us; speedup vs baseline: 1.0927x; 1.0927x over previous
//
#include <hip/hip_runtime.h>

typedef _Float16 half_t;
typedef _Float16 v8h __attribute__((ext_vector_type(8)));
typedef _Float16 h2  __attribute__((ext_vector_type(2)));
typedef float v4f __attribute__((ext_vector_type(4)));

#define XTP 40   // xt LDS row pitch (halves): 32 data + 8 pad
#define HP  72   // h  LDS row pitch (halves): 64 data + 8 pad

typedef __attribute__((address_space(3))) unsigned int lds_u32;
typedef const __attribute__((address_space(1))) unsigned int glb_u32;

// async 16B/lane global->LDS DMA: lds dest = l + lane*16 (HW), src = g + lane*16
__device__ __forceinline__ void dma16(const half_t* g, half_t* l, int lane) {
  __builtin_amdgcn_global_load_lds((glb_u32*)(g + lane * 8), (lds_u32*)(l), 16, 0, 0);
}

// raw waitcnt: vmcnt(N), lgkmcnt/expcnt = no-wait (gfx9 encoding)
#define WAITVM(N) __builtin_amdgcn_s_waitcnt(0xF70 | (N))
#define SCHED0()  __builtin_amdgcn_sched_barrier(0)

// half-broadcast helpers: duplicate one 16-bit half across a 32-bit word
__device__ __forceinline__ unsigned dup_lo(unsigned w) { return (w << 16) | (w & 0xffffu); }
__device__ __forceinline__ unsigned dup_hi(unsigned w) { return (w >> 16) | (w & 0xffff0000u); }

// v8h * broadcast-half via 4x v_pk_mul_f16 (replaces the scalarized vector*element)
__device__ __forceinline__ v8h mul_bcast(v8h h, unsigned xx) {
  union U { v8h v; h2 p[4]; unsigned u[4]; } a, r, x;
  a.v = h; x.u[0] = xx;
#pragma unroll
  for (int i = 0; i < 4; ++i) r.p[i] = a.p[i] * x.p[0];
  return r.v;
}

// ===== merged W prep: W (128,K) f32 -> f16 chunked [K/8][128][8] for all 3 layers =====
// (round-0 verbatim -- harness-verified layout)
__global__ __launch_bounds__(256) void prep_w_all(const float* __restrict__ W0,
                                                  const float* __restrict__ W1,
                                                  const float* __restrict__ W2,
                                                  half_t* __restrict__ w0h,
                                                  half_t* __restrict__ w1h,
                                                  half_t* __restrict__ w2h) {
  int i = blockIdx.x * 256 + threadIdx.x;         // 0..81919 (wave-uniform segments)
  const float* src; half_t* dst; int ktot; int j;
  if (i < 16384)      { src = W0; dst = w0h; ktot = 1024; j = i; }
  else if (i < 49152) { src = W1; dst = w1h; ktot = 2048; j = i - 16384; }
  else                { src = W2; dst = w2h; ktot = 2048; j = i - 49152; }
  int o = j & 127, k8 = j >> 7;
  const float* s = src + (size_t)o * ktot + k8 * 8;
  float4 f0 = *(const float4*)s;
  float4 f1 = *(const float4*)(s + 4);
  union { half_t h[8]; uint4 u; } pk;
  pk.h[0] = (half_t)f0.x; pk.h[1] = (half_t)f0.y; pk.h[2] = (half_t)f0.z; pk.h[3] = (half_t)f0.w;
  pk.h[4] = (half_t)f1.x; pk.h[5] = (half_t)f1.y; pk.h[6] = (half_t)f1.z; pk.h[7] = (half_t)f1.w;
  *(uint4*)(dst + (size_t)j * 8) = pk.u;
}

// ============ one CIN layer (device): Y = relu(W @ Z + b), Z built on the fly ============
// Round-0 skeleton verbatim (best measured: 88.6us): wave tile 64(o) x 32(2b x 16e),
// W via global_load_lds 4-slab ring, depth 3, raw vmcnt(N)+s_barrier per step.
// ROUND 9 single change: bfr built with dup+v_pk_mul_f16 (was scalarized vec*elem).
template <int G, int KTOT, int KEEP, int OUT_BASE, bool H_OUT, bool H_IS_X>
__device__ __forceinline__ void layer(const half_t* __restrict__ wgt,
                                      const float* __restrict__ bias,
                                      half_t* __restrict__ xt_lds,
                                      half_t* __restrict__ h_lds,
                                      half_t* __restrict__ w_ring,
                                      float* __restrict__ out,
                                      size_t b0, int tid, int phase) {
  constexpr int SPO = (G == 64) ? 16 : 8;   // steps per f-octet (SPO % 4 == 0)
  constexpr int NOCT = (KTOT / 32) / SPO;   // 4
  constexpr int NSEL = (G == 64) ? 2 : 1;
  const int lane = tid & 63;
  const int wv = tid >> 6;                  // 0..7
  const int wm = (wv & 1) * 64;             // o offset
  const int wb = (wv >> 1) * 2;             // local batch offset (0,2,4,6)
  const int col = lane & 15;                // = e
  const int kq = lane >> 4;                 // k-quad (fixed per lane)

  int lrow[2];
#pragma unroll
  for (int ni = 0; ni < 2; ++ni) lrow[ni] = (wb + ni) * 16 + col;

  __syncthreads();   // prior xt staging / previous layer's h_lds writes visible

  // ---- h fragments: register-resident for the whole K-loop ----
  const half_t* hb = H_IS_X ? xt_lds : h_lds;
  const int hpitch = H_IS_X ? XTP : HP;
  v8h hreg[2][NSEL];
#pragma unroll
  for (int ni = 0; ni < 2; ++ni) {
    const half_t* hp = hb + lrow[ni] * hpitch + kq * 8;
    hreg[ni][0] = *(const v8h*)hp;
    if (NSEL > 1) hreg[ni][NSEL - 1] = *(const v8h*)(hp + 32);
  }

  // ---- prologue: DMA slabs 0..2 (rotated), 1 dma16 (1KB) per wave per slab ----
#pragma unroll
  for (int p = 0; p < 3; ++p) {
    const half_t* wsrc = wgt + (size_t)(phase * SPO + p) * 4096;
    dma16(wsrc + wv * 512, w_ring + p * 4096 + wv * 512, lane);
  }
  __syncthreads();   // DMA 0..2 drained (full drain, only here per layer)

  v4f acc[4][2] = {};

  // ---- main octets (all but last) ----
#pragma unroll 1
  for (int oi = 0; oi < NOCT - 1; ++oi) {
    const int oct_a = (oi + phase) & 3;
    const int next_a = (oi + 1 + phase) & 3;
    unsigned xwu[2][4];
#pragma unroll
    for (int ni = 0; ni < 2; ++ni) {
      uint4 q = *(const uint4*)(xt_lds + lrow[ni] * XTP + oct_a * 8);
      xwu[ni][0] = q.x; xwu[ni][1] = q.y; xwu[ni][2] = q.z; xwu[ni][3] = q.w;
    }
#pragma unroll
    for (int t = 0; t < SPO; ++t) {
      SCHED0(); WAITVM(2); __builtin_amdgcn_s_barrier(); SCHED0();
      {  // prefetch slab at pipeline distance +3
        const int tp = t + 3;
        const half_t* wsrc = (tp < SPO)
            ? wgt + (size_t)(oct_a * SPO + tp) * 4096
            : wgt + (size_t)(next_a * SPO + (tp - SPO)) * 4096;
        dma16(wsrc + wv * 512, w_ring + (tp & 3) * 4096 + wv * 512, lane);
      }
      const half_t* rb = w_ring + (t & 3) * 4096;
      const int j = (G == 64) ? (t >> 1) : t;
      const int sel = (G == 64) ? (t & 1) : 0;
      v8h a[4], bfr[2];
#pragma unroll
      for (int mi = 0; mi < 4; ++mi)
        a[mi] = *(const v8h*)(rb + (kq * 128 + wm + mi * 16 + col) * 8);
#pragma unroll
      for (int ni = 0; ni < 2; ++ni) {
        const unsigned w = xwu[ni][j >> 1];
        bfr[ni] = mul_bcast(hreg[ni][sel], (j & 1) ? dup_hi(w) : dup_lo(w));
      }
#pragma unroll
      for (int mi = 0; mi < 4; ++mi)
#pragma unroll
        for (int ni = 0; ni < 2; ++ni)
          acc[mi][ni] = __builtin_amdgcn_mfma_f32_16x16x32_f16(a[mi], bfr[ni], acc[mi][ni], 0, 0, 0);
    }
  }

  // ---- final octet (peeled pipeline tail) ----
  {
    const int oct_a = (NOCT - 1 + phase) & 3;
    unsigned xwu[2][4];
#pragma unroll
    for (int ni = 0; ni < 2; ++ni) {
      uint4 q = *(const uint4*)(xt_lds + lrow[ni] * XTP + oct_a * 8);
      xwu[ni][0] = q.x; xwu[ni][1] = q.y; xwu[ni][2] = q.z; xwu[ni][3] = q.w;
    }
#pragma unroll
    for (int t = 0; t < SPO; ++t) {
      SCHED0();
      if (t < SPO - 2) { WAITVM(2); } else if (t == SPO - 2) { WAITVM(1); } else { WAITVM(0); }
      __builtin_amdgcn_s_barrier(); SCHED0();
      if (t + 3 < SPO) {
        const int tp = t + 3;
        const half_t* wsrc = wgt + (size_t)(oct_a * SPO + tp) * 4096;
        dma16(wsrc + wv * 512, w_ring + (tp & 3) * 4096 + wv * 512, lane);
      }
      const half_t* rb = w_ring + (t & 3) * 4096;
      const int j = (G == 64) ? (t >> 1) : t;
      const int sel = (G == 64) ? (t & 1) : 0;
      v8h a[4], bfr[2];
#pragma unroll
      for (int mi = 0; mi < 4; ++mi)
        a[mi] = *(const v8h*)(rb + (kq * 128 + wm + mi * 16 + col) * 8);
#pragma unroll
      for (int ni = 0; ni < 2; ++ni) {
        const unsigned w = xwu[ni][j >> 1];
        bfr[ni] = mul_bcast(hreg[ni][sel], (j & 1) ? dup_hi(w) : dup_lo(w));
      }
#pragma unroll
      for (int mi = 0; mi < 4; ++mi)
#pragma unroll
        for (int ni = 0; ni < 2; ++ni)
          acc[mi][ni] = __builtin_amdgcn_mfma_f32_16x16x32_f16(a[mi], bfr[ni], acc[mi][ni], 0, 0, 0);
    }
  }

  // ---- epilogue: bias + relu; rows>=64 -> h_lds (B-layout); rows<KEEP -> sum_e -> out ----
  // Safe without extra barrier: all waves' hreg loads finished >=KTOT/32 barriers ago;
  // h_lds is read by nobody between K-loop start and the next layer's entry sync.
#pragma unroll
  for (int mi = 0; mi < 4; ++mi) {
    const int o_base = wm + mi * 16 + kq * 4;     // C rows o_base..o_base+3
    float4 b4 = *(const float4*)(bias + o_base);
#pragma unroll
    for (int ni = 0; ni < 2; ++ni) {
      const int bb = wb + ni;
      float v[4];
#pragma unroll
      for (int r = 0; r < 4; ++r)
        v[r] = fmaxf(acc[mi][ni][r] + (&b4.x)[r], 0.0f);
      if (H_OUT && o_base >= 64) {                // wave-uniform (== wm==64)
        union { half_t h[4]; uint2 u; } pk;
#pragma unroll
        for (int r = 0; r < 4; ++r) pk.h[r] = (half_t)v[r];
        *(uint2*)(h_lds + (bb * 16 + col) * HP + (o_base - 64)) = pk.u;
      }
      if (o_base < KEEP) {                        // wave-uniform
#pragma unroll
        for (int r = 0; r < 4; ++r) {
          float sv = v[r];
          sv += __shfl_xor(sv, 1);
          sv += __shfl_xor(sv, 2);
          sv += __shfl_xor(sv, 4);
          sv += __shfl_xor(sv, 8);                // sum over e (16-lane group)
          if (col == 0) out[(b0 + bb) * 256 + OUT_BASE + o_base + r] = sv;
        }
      }
    }
  }
}

// ============ fused CIN: all 3 layers, one block = 8 batch elements ============
// 512 thr (8 waves), grid 512 -> 2 blocks/CU -> 4 waves/SIMD.
// LDS: xt 10KB + h 18KB + W ring 32KB = ~60KB -> 2 blocks co-resident (120KB < 160KB).
__global__ __launch_bounds__(512, 4) void cin_fused(const float* __restrict__ x,
                                                    const half_t* __restrict__ w0h,
                                                    const half_t* __restrict__ w1h,
                                                    const half_t* __restrict__ w2h,
                                                    const float* __restrict__ b0p,
                                                    const float* __restrict__ b1p,
                                                    const float* __restrict__ b2p,
                                                    float* __restrict__ out) {
  __shared__ __align__(16) half_t xt_lds[128 * XTP];
  __shared__ __align__(16) half_t h_lds[128 * HP];
  __shared__ __align__(16) half_t w_ring[4 * 4096];

  const int tid = threadIdx.x;
  const size_t b0 = (size_t)blockIdx.x * 8;
  const int phase = (blockIdx.x >> 3) & 3;     // co-XCD blocks start on different octets

  // ---- stage xt from x f32 (b,f,e) -> LDS (b,e) rows x 32 f, f16 ----
#pragma unroll
  for (int i = 0; i < 2; ++i) {
    int idx = (i * 512 + tid) * 4;             // 0..4095 by 4 (e%4==0 within one f,b)
    float4 v = *(const float4*)(x + b0 * 512 + idx);
    int e = idx & 15, f = (idx >> 4) & 31, b = idx >> 9;
    half_t* d = xt_lds + (b * 16 + e) * XTP + f;
    d[0 * XTP] = (half_t)v.x;
    d[1 * XTP] = (half_t)v.y;
    d[2 * XTP] = (half_t)v.z;
    d[3 * XTP] = (half_t)v.w;
  }

  // layer 0: G=32 (h = x0), keep o<64 -> out ch [0,64), o>=64 -> h_lds
  layer<32, 1024, 64, 0, true, true>(w0h, b0p, xt_lds, h_lds, w_ring, out, b0, tid, phase);
  // layer 1: G=64, keep o<64 -> out ch [64,128), o>=64 -> h_lds (overwrite)
  layer<64, 2048, 64, 64, true, false>(w1h, b1p, xt_lds, h_lds, w_ring, out, b0, tid, phase);
  // layer 2: G=64, keep all 128 -> out ch [128,256)
  layer<64, 2048, 128, 128, false, false>(w2h, b2p, xt_lds, h_lds, w_ring, out, b0, tid, phase);
}

extern "C" void kernel_launch(void* const* d_in, const int* in_sizes, int n_in,
                              void* d_out, int out_size, void* d_ws, size_t ws_size,
                              hipStream_t stream) {
  const float* x  = (const float*)d_in[0];
  const float* W0 = (const float*)d_in[1];
  const float* b0 = (const float*)d_in[2];
  const float* W1 = (const float*)d_in[3];
  const float* b1 = (const float*)d_in[4];
  const float* W2 = (const float*)d_in[5];
  const float* b2 = (const float*)d_in[6];
  float* out = (float*)d_out;
  char* ws = (char*)d_ws;

  half_t* w0h = (half_t*)(ws);                       // 256 KB
  half_t* w1h = (half_t*)(ws + (256u << 10));        // 512 KB
  half_t* w2h = (half_t*)(ws + (768u << 10));        // 512 KB

  prep_w_all<<<320, 256, 0, stream>>>(W0, W1, W2, w0h, w1h, w2h);
  cin_fused<<<512, 512, 0, stream>>>(x, w0h, w1h, w2h, b0, b1, b2, out);
}